// Round 1
// baseline (87.784 us; speedup 1.0000x reference)
//
#include <hip/hip_runtime.h>

#define H 1024
#define N 64
#define L 2048
#define TPB 256          // main-kernel threads per block (one block per h)
#define KK (L / TPB)     // l-positions per thread = 8

#define INV2PI 0.15915494309189535f

__device__ __forceinline__ float fexp(float x) {
    // e^x via hardware v_exp_f32 (2^x)
    return __expf(x);
}

// Precompute per (h,n):
//   dtA = exp(log_dt[h]) * A[n]                  (complex)
//   s   = exp(dtA * TPB)                         (chunk step, complex)
//   cm  = 2 * C[h,n] * (exp(dtA) - 1) / A[n]     (complex)
// Layout: P1[idx] = (dtA_re, dtA_im, s_re, s_im), P2[idx] = (cm_re, cm_im)
__global__ void s4d_precomp(const float* __restrict__ log_dt,
                            const float* __restrict__ Cv,
                            const float* __restrict__ Av,
                            float4* __restrict__ P1,
                            float2* __restrict__ P2)
{
    int idx = blockIdx.x * blockDim.x + threadIdx.x;   // h*N + n
    if (idx >= H * N) return;
    int h = idx >> 6;
    int n = idx & (N - 1);

    float dt = fexp(log_dt[h]);
    float ar = Av[2 * n], ai = Av[2 * n + 1];
    float dr = dt * ar, di = dt * ai;

    // r = exp(dtA)
    float mr  = fexp(dr);
    float rev = di * INV2PI;
    rev -= floorf(rev);
    float rr = mr * __builtin_amdgcn_cosf(rev);
    float ri = mr * __builtin_amdgcn_sinf(rev);

    // s = exp(dtA * TPB)  (computed directly for precision)
    float ms   = fexp(dr * (float)TPB);
    float revs = di * ((float)TPB * INV2PI);
    revs -= floorf(revs);
    float sr = ms * __builtin_amdgcn_cosf(revs);
    float si = ms * __builtin_amdgcn_sinf(revs);

    // cm = 2 * C * (r - 1) / a   (complex divide via conj(a)/|a|^2)
    float cr = Cv[2 * idx], ci = Cv[2 * idx + 1];
    float er = rr - 1.0f, ei = ri;
    float tr = cr * er - ci * ei;
    float ti = cr * ei + ci * er;
    float inv = 2.0f / (ar * ar + ai * ai);
    float cmr = (tr * ar + ti * ai) * inv;
    float cmi = (ti * ar - tr * ai) * inv;

    P1[idx] = make_float4(dr, di, sr, si);
    P2[idx] = make_float2(cmr, cmi);
}

// One block per h. Thread t owns l = t + TPB*k, k = 0..KK-1.
// Per n: w = cm * exp(dtA * t)  (3 transcendentals), then KK steps of
// w *= s (complex), accumulating Re(w) into acc[k].
__global__ __launch_bounds__(TPB) void s4d_main(const float4* __restrict__ P1,
                                                const float2* __restrict__ P2,
                                                float* __restrict__ out)
{
    __shared__ float4 l1[N];
    __shared__ float2 l2[N];

    const int h = blockIdx.x;
    const int t = threadIdx.x;
    if (t < N) {
        l1[t] = P1[h * N + t];
        l2[t] = P2[h * N + t];
    }
    __syncthreads();

    float acc[KK];
#pragma unroll
    for (int k = 0; k < KK; ++k) acc[k] = 0.0f;

    const float tf = (float)t;

#pragma unroll 2
    for (int n = 0; n < N; ++n) {
        float4 a = l1[n];   // dtA_re, dtA_im, s_re, s_im  (LDS broadcast)
        float2 c = l2[n];   // cm_re, cm_im

        // w0 = cm * exp(dtA * t)
        float m   = fexp(a.x * tf);
        float rev = (a.y * tf) * INV2PI;
        rev -= floorf(rev);
        float cs = __builtin_amdgcn_cosf(rev);
        float sn = __builtin_amdgcn_sinf(rev);
        float wre = m * (c.x * cs - c.y * sn);
        float wim = m * (c.x * sn + c.y * cs);

#pragma unroll
        for (int k = 0; k < KK; ++k) {
            acc[k] += wre;
            float nr = wre * a.z - wim * a.w;
            wim      = wre * a.w + wim * a.z;
            wre      = nr;
        }
    }

    float* o = out + h * L + t;
#pragma unroll
    for (int k = 0; k < KK; ++k) o[k * TPB] = acc[k];   // coalesced per k
}

extern "C" void kernel_launch(void* const* d_in, const int* in_sizes, int n_in,
                              void* d_out, int out_size, void* d_ws, size_t ws_size,
                              hipStream_t stream) {
    const float* log_dt = (const float*)d_in[0];
    const float* Cv     = (const float*)d_in[1];   // (H, N, 2)
    const float* Av     = (const float*)d_in[2];   // (N, 2)
    float* out          = (float*)d_out;           // (H, L) fp32

    float4* P1 = (float4*)d_ws;                                  // H*N*16 B
    float2* P2 = (float2*)((char*)d_ws + (size_t)H * N * sizeof(float4)); // H*N*8 B

    s4d_precomp<<<(H * N + 255) / 256, 256, 0, stream>>>(log_dt, Cv, Av, P1, P2);
    s4d_main<<<H, TPB, 0, stream>>>(P1, P2, out);
}

// Round 2
// 79.688 us; speedup vs baseline: 1.1016x; 1.1016x over previous
//
#include <hip/hip_runtime.h>

#define H 1024
#define N 64
#define L 2048
#define TPB 256          // threads per block; one block per h
#define KK (L / TPB)     // l-positions per thread = 8

#define INV2PI 0.15915494309189535f

typedef float f32x2 __attribute__((ext_vector_type(2)));

// ---- packed-f32 helpers (CDNA2+ v_pk_*_f32; 2 fp32 ops per instruction) ----

__device__ __forceinline__ f32x2 pk_add(f32x2 a, f32x2 b) {
    f32x2 d;
    asm("v_pk_add_f32 %0, %1, %2" : "=v"(d) : "v"(a), "v"(b));
    return d;
}

// complex multiply r = w * s, layout (re, im) in (lo, hi)
// t = (w.re*s.re, w.im*s.re)           pk_mul, S1 broadcast lo
// r = (t.lo - w.im*s.im, t.hi + w.re*s.im)
__device__ __forceinline__ f32x2 cmul(f32x2 w, f32x2 s) {
    f32x2 t, r;
    asm("v_pk_mul_f32 %0, %1, %2 op_sel_hi:[1,0]"
        : "=v"(t) : "v"(w), "v"(s));
    asm("v_pk_fma_f32 %0, %1, %2, %3 op_sel:[1,1,0] op_sel_hi:[0,1,1] neg_lo:[1,0,0]"
        : "=v"(r) : "v"(w), "v"(s), "v"(t));
    return r;
}

// Fused: per-block precompute of (dtA, s=exp(dtA*TPB), cm=2C(e^dtA-1)/A) into
// LDS, then Vandermonde-by-recurrence. Thread t owns l = t + TPB*k.
__global__ __launch_bounds__(TPB) void s4d_fused(const float* __restrict__ log_dt,
                                                 const float* __restrict__ Cv,
                                                 const float* __restrict__ Av,
                                                 float* __restrict__ out)
{
    __shared__ float4 p1[N];   // dr, di*INV2PI, s_re, s_im
    __shared__ f32x2 p2[N];    // cm_re, cm_im

    const int h = blockIdx.x;
    const int t = threadIdx.x;

    if (t < N) {
        float dt = __expf(log_dt[h]);
        float2 a2 = ((const float2*)Av)[t];
        float ar = a2.x, ai = a2.y;
        float dr = dt * ar;
        float direv = dt * ai * INV2PI;   // phase in revolutions per l

        // r = exp(dtA)
        float mr  = __expf(dr);
        float rev = direv - floorf(direv);
        float rr = mr * __builtin_amdgcn_cosf(rev);
        float ri = mr * __builtin_amdgcn_sinf(rev);

        // s = exp(dtA * TPB)
        float ms   = __expf(dr * (float)TPB);
        float revs = direv * (float)TPB;
        revs -= floorf(revs);
        float sr = ms * __builtin_amdgcn_cosf(revs);
        float si = ms * __builtin_amdgcn_sinf(revs);

        // cm = 2 * C * (r - 1) / a
        float2 c2 = ((const float2*)Cv)[h * N + t];
        float er = rr - 1.0f, ei = ri;
        float tr = c2.x * er - c2.y * ei;
        float ti = c2.x * ei + c2.y * er;
        float inv = 2.0f / (ar * ar + ai * ai);
        f32x2 cm;
        cm.x = (tr * ar + ti * ai) * inv;
        cm.y = (ti * ar - tr * ai) * inv;

        p1[t] = make_float4(dr, direv, sr, si);
        p2[t] = cm;
    }
    __syncthreads();

    f32x2 acc[KK];
#pragma unroll
    for (int k = 0; k < KK; ++k) acc[k] = (f32x2)(0.0f);

    const float tf = (float)t;

#pragma unroll 2
    for (int n = 0; n < N; ++n) {
        float4 a   = p1[n];    // LDS broadcast
        f32x2 cmv  = p2[n];

        // w0 = cm * exp(dtA * t)
        float m   = __expf(a.x * tf);
        float rev = a.y * tf;
        rev -= floorf(rev);
        f32x2 e;
        e.x = m * __builtin_amdgcn_cosf(rev);
        e.y = m * __builtin_amdgcn_sinf(rev);
        f32x2 w = cmul(e, cmv);

        f32x2 s;
        s.x = a.z; s.y = a.w;

#pragma unroll
        for (int k = 0; k < KK; ++k) {
            acc[k] = pk_add(acc[k], w);   // carries (re,im); re used at end
            w = cmul(w, s);               // final iteration DCE'd (non-volatile asm)
        }
    }

    float* o = out + h * L + t;
#pragma unroll
    for (int k = 0; k < KK; ++k) o[k * TPB] = acc[k].x;   // coalesced per k
}

extern "C" void kernel_launch(void* const* d_in, const int* in_sizes, int n_in,
                              void* d_out, int out_size, void* d_ws, size_t ws_size,
                              hipStream_t stream) {
    const float* log_dt = (const float*)d_in[0];
    const float* Cv     = (const float*)d_in[1];   // (H, N, 2)
    const float* Av     = (const float*)d_in[2];   // (N, 2)
    float* out          = (float*)d_out;           // (H, L) fp32

    s4d_fused<<<H, TPB, 0, stream>>>(log_dt, Cv, Av, out);
}

// Round 5
// 75.490 us; speedup vs baseline: 1.1629x; 1.0556x over previous
//
#include <hip/hip_runtime.h>

#define H 1024
#define N 64
#define L 2048
#define TPB 256          // threads per block; one block per h
#define KK (L / TPB)     // l-positions per thread = 8

#define INV2PI 0.15915494309189535f

typedef float f32x2 __attribute__((ext_vector_type(2)));

// ---- packed-f32 helpers (v_pk_*_f32: 2 fp32 ops per instruction) ----

__device__ __forceinline__ f32x2 pk_add(f32x2 a, f32x2 b) {
    f32x2 d;
    asm("v_pk_add_f32 %0, %1, %2" : "=v"(d) : "v"(a), "v"(b));
    return d;
}

// complex multiply r = w * s, layout (re, im) = (lo, hi)
// t = (w.re*s.re, w.im*s.re); r = (t.lo - w.im*s.im, t.hi + w.re*s.im)
// Verified passing in rounds 1-2.
__device__ __forceinline__ f32x2 cmul(f32x2 w, f32x2 s) {
    f32x2 t, r;
    asm("v_pk_mul_f32 %0, %1, %2 op_sel_hi:[1,0]"
        : "=v"(t) : "v"(w), "v"(s));
    asm("v_pk_fma_f32 %0, %1, %2, %3 op_sel:[1,1,0] op_sel_hi:[0,1,1] neg_lo:[1,0,0]"
        : "=v"(r) : "v"(w), "v"(s), "v"(t));
    return r;
}

__device__ __forceinline__ f32x2 cexp_rev(float mag_arg, float rev_arg) {
    // exp(mag_arg) * (cos(2*pi*rev_arg), sin(2*pi*rev_arg))
    float m = __expf(mag_arg);
    float rv = rev_arg - floorf(rev_arg);
    f32x2 e;
    e.x = m * __builtin_amdgcn_cosf(rv);
    e.y = m * __builtin_amdgcn_sinf(rv);
    return e;
}

// One block per h. Thread t owns l = t + TPB*k.
// Phase 1: build per-n tables in LDS:
//   W16[n][j] = cm[n] * exp(dtA*16j)   (j<16)   cm = 2C(e^dtA-1)/A
//   E1 [n][j] = exp(dtA*j)             (j<16)
//   S  [n]    = exp(dtA*256)
// Phase 2 (trans-free): w0 = W16[n][t>>4] * E1[n][t&15]; then KK steps of
// w *= S[n], accumulating Re(w).
__global__ __launch_bounds__(TPB) void s4d_fused(const float* __restrict__ log_dt,
                                                 const float* __restrict__ Cv,
                                                 const float* __restrict__ Av,
                                                 float* __restrict__ out)
{
    __shared__ f32x2 W16[N][16];   // 8 KB
    __shared__ f32x2 E1t[N][16];   // 8 KB
    __shared__ f32x2 Sv[N];        // 512 B

    const int h = blockIdx.x;
    const int t = threadIdx.x;

    // ---------- phase 1: tables ----------
    {
        const int n  = t >> 2;          // 4 threads per n
        const int j0 = (t & 3) << 2;    // each computes 4 j's
        float dt = __expf(log_dt[h]);

        float2 a2 = ((const float2*)Av)[n];
        float dr    = dt * a2.x;
        float direv = dt * a2.y * INV2PI;   // phase in revolutions per l

        // cm = 2 * C * (exp(dtA) - 1) / A
        f32x2 r1 = cexp_rev(dr, direv);
        float2 c2 = ((const float2*)Cv)[h * N + n];
        float er = r1.x - 1.0f, ei = r1.y;
        float tr = c2.x * er - c2.y * ei;
        float ti = c2.x * ei + c2.y * er;
        float inv = 2.0f / (a2.x * a2.x + a2.y * a2.y);
        f32x2 cm;
        cm.x = (tr * a2.x + ti * a2.y) * inv;
        cm.y = (ti * a2.x - tr * a2.y) * inv;

#pragma unroll
        for (int jj = 0; jj < 4; ++jj) {
            float fj = (float)(j0 + jj);
            E1t[n][j0 + jj] = cexp_rev(dr * fj, direv * fj);
            float fg = fj * 16.0f;
            W16[n][j0 + jj] = cmul(cexp_rev(dr * fg, direv * fg), cm);
        }

        if (t < N) {                     // S[t] = exp(dtA[t]*256)
            float2 a2b = ((const float2*)Av)[t];
            float drb = dt * a2b.x;
            float dib = dt * a2b.y * INV2PI;
            Sv[t] = cexp_rev(drb * 256.0f, dib * 256.0f);
        }
    }
    __syncthreads();

    // ---------- phase 2: trans-free recurrence ----------
    f32x2 acc[KK];
#pragma unroll
    for (int k = 0; k < KK; ++k) acc[k] = (f32x2)(0.0f);

    const int jhi = t >> 4;    // W16 index (broadcast within 16-lane groups)
    const int jlo = t & 15;    // E1 index (16 distinct 8B entries, conflict-free)

#pragma unroll 4
    for (int n = 0; n < N; ++n) {
        f32x2 w16 = W16[n][jhi];
        f32x2 e1  = E1t[n][jlo];
        f32x2 s   = Sv[n];
        f32x2 w = cmul(e1, w16);       // w0 = cm * exp(dtA * t)

#pragma unroll
        for (int k = 0; k < KK; ++k) {
            acc[k] = pk_add(acc[k], w);
            w = cmul(w, s);            // last iteration DCE'd
        }
    }

    float* o = out + h * L + t;
#pragma unroll
    for (int k = 0; k < KK; ++k) o[k * TPB] = acc[k].x;   // coalesced per k
}

extern "C" void kernel_launch(void* const* d_in, const int* in_sizes, int n_in,
                              void* d_out, int out_size, void* d_ws, size_t ws_size,
                              hipStream_t stream) {
    const float* log_dt = (const float*)d_in[0];
    const float* Cv     = (const float*)d_in[1];   // (H, N, 2)
    const float* Av     = (const float*)d_in[2];   // (N, 2)
    float* out          = (float*)d_out;           // (H, L) fp32

    s4d_fused<<<H, TPB, 0, stream>>>(log_dt, Cv, Av, out);
}